// Round 14
// baseline (41.521 us; speedup 1.0000x reference)
//
#include <hip/hip_runtime.h>
#include <hip/hip_fp16.h>
#include <stdint.h>

// Problem constants: IMG=512, CUT_SIZE=224, CUTN=64, B=4, C=3; sizes in [224,511]
constexpr int S   = 224;
constexpr int Wim = 512;
constexpr int Him = 512;
constexpr int PLANES = 12;                   // B*C
constexpr int N   = 64;
constexpr int SB  = 16;                      // source rows per band
constexpr int NBANDS = Him / SB;             // 32
constexpr int NGRP = 8;                      // cutouts per block
constexpr int GROUPS = N / NGRP;             // 8
constexpr int TILES = PLANES * NBANDS;       // 384 (plane,band) tiles
constexpr int TPX   = TILES / 8;             // 48 tiles per XCD
constexpr int WPB   = 4;                     // 256 threads
constexpr int GRID  = TILES * GROUPS;        // 3072
constexpr int ROWP  = 516;                   // pair-slots per row -> byte stride 2064

typedef float    f32x4 __attribute__((ext_vector_type(4)));
typedef _Float16 f16x2 __attribute__((ext_vector_type(2)));
typedef uint32_t u32x4 __attribute__((ext_vector_type(4)));

// iy0 exactly as reference computes it
__device__ __forceinline__ int iy0_of(int i, float scale, int sz) {
    const float sy = fmaxf(scale * ((float)i + 0.5f) - 0.5f, 0.0f);
    return min((int)floorf(sy), sz - 1);
}

__global__ __launch_bounds__(256) void cutouts_kernel(
    const float* __restrict__ x,
    const int*   __restrict__ sizes,
    const int*   __restrict__ offx,
    const int*   __restrict__ offy,
    float*       __restrict__ out)
{
    // band staged as packed f16 pairs: pb[r][d] = (f16 v_d, f16 v_{d+1})
    __shared__ uint32_t pb[SB + 1][ROWP];    // 35,088 B -> 4 blocks/CU

    const int lane = threadIdx.x & 63;
    const int wv   = threadIdx.x >> 6;       // 0..3

    // decode: XCD-affine (plane,band) tile (R12 structure)
    const int xcd   = blockIdx.x & 7;
    const int local = blockIdx.x >> 3;       // 0..383
    const int tk    = local >> 3;            // tile-in-xcd 0..47
    const int g     = local & 7;             // cutout group 0..7
    const int t     = xcd * TPX + tk;        // 0..383
    const int pi    = t >> 5;                // plane 0..11
    const int b     = t & 31;                // band 0..31

    const float* plane = x + (size_t)pi * (Him * Wim);

    // ---- stage band as f16 pairs: 34 chunks (17 rows x 2 halves), 9/wave ----
    f32x4 sv[9]; float se[9];
    #pragma unroll
    for (int k = 0; k < 9; ++k) {            // issue ALL loads first
        const int c    = min(wv + 4 * k, 33);          // dup chunk 33: benign
        const int row  = c >> 1, half = c & 1;
        const int srow = min(SB * b + row, Him - 1);   // dup row (wt-0 only)
        const int c0   = half * 256 + 4 * lane;
        const float* rp = plane + (size_t)srow * Wim + c0;
        sv[k] = *(const f32x4*)rp;                     // cols c0..c0+3
        se[k] = plane[(size_t)srow * Wim + min(c0 + 4, Wim - 1)]; // overlap col
    }
    #pragma unroll
    for (int k = 0; k < 9; ++k) {            // convert + pair + LDS write
        const int c   = min(wv + 4 * k, 33);
        const int row = c >> 1, half = c & 1;
        u32x4 w;
        w.x = __builtin_bit_cast(uint32_t, __builtin_amdgcn_cvt_pkrtz(sv[k].x, sv[k].y));
        w.y = __builtin_bit_cast(uint32_t, __builtin_amdgcn_cvt_pkrtz(sv[k].y, sv[k].z));
        w.z = __builtin_bit_cast(uint32_t, __builtin_amdgcn_cvt_pkrtz(sv[k].z, sv[k].w));
        w.w = __builtin_bit_cast(uint32_t, __builtin_amdgcn_cvt_pkrtz(sv[k].w, se[k]));
        *(u32x4*)&pb[row][half * 256 + 4 * lane] = w;  // ds_write_b128, 16B-aligned
    }

    // in-lane parallel first_ge: lanes 0..7 -> i_lo, lanes 8..15 -> i_hi
    int flv;
    {
        const int   idx = lane & 7;
        const int   nn_ = g * NGRP + idx;
        const int   szl = sizes[nn_];
        const int   oyl = offy[nn_];
        const float scl = (float)szl / (float)S;
        const int   P   = SB * b - oyl + ((lane & 8) ? SB : 0);
        int res;
        if (P <= 0) res = 0;
        else if (P > szl - 1) res = S;
        else {
            const float cc = ((float)P + 0.5f) / scl - 0.5f;
            int i = (int)ceilf(fminf(fmaxf(cc, 0.0f), (float)S));
            while (i > 0 && iy0_of(i - 1, scl, szl) >= P) --i;
            while (i < S && iy0_of(i, scl, szl) < P) ++i;
            res = i;
        }
        flv = res;
    }

    __syncthreads();                          // drains vm+lgkm, then barrier

    #pragma unroll 1
    for (int nn = 0; nn < NGRP; ++nn) {
        const int i_lo = __builtin_amdgcn_readlane(flv, nn);
        const int i_hi = __builtin_amdgcn_readlane(flv, nn + 8);
        if (i_lo >= i_hi) continue;

        const int n  = g * NGRP + nn;
        const int sz = sizes[n];
        const int oy = offy[n];
        const int ox = offx[n];
        const float scale = (float)sz / (float)S;
        const int   L     = SB * b - oy;

        // horizontal params once per (wave,cutout)
        int dv[4]; float fxv[4];
        #pragma unroll
        for (int r = 0; r < 4; ++r) {
            const int   px = r * 64 + lane;
            const float sx = fmaxf(scale * ((float)px + 0.5f) - 0.5f, 0.0f);
            const float fi = floorf(sx);
            fxv[r] = sx - fi;                          // ix0 <= sz-1 (sz>=224)
            dv[r]  = ox + (int)fi;                     // d <= 511; pair handles d+1
        }

        float* oplane = out + (size_t)(n * PLANES + pi) * (S * S);

        for (int i = i_lo + wv; i < i_hi; i += WPB) {
            const float sy  = fmaxf(scale * ((float)i + 0.5f) - 0.5f, 0.0f);
            const float fiy = floorf(sy);
            const float fy  = sy - fiy;                // frac BEFORE clamp
            const int   rel = (int)fiy - L;            // in [0, SB-1] (partition)
            const uint32_t* r0 = &pb[rel][0];          // rel+1 = +ROWP imm offset
            float* orow = oplane + (size_t)i * S;

            #pragma unroll
            for (int r = 0; r < 4; ++r) {
                if (r < 3 || lane < 32) {              // 224 = 3*64 + 32
                    const int d  = dv[r];
                    const uint32_t u0 = r0[d];         // ds_read_b32
                    const uint32_t u1 = r0[d + ROWP];  // ds_read_b32 offset:2064
                    const f16x2 a = __builtin_bit_cast(f16x2, u0);
                    const f16x2 c = __builtin_bit_cast(f16x2, u1);
                    const float ax = (float)a.x, ay = (float)a.y;
                    const float cx = (float)c.x, cy = (float)c.y;
                    const float f  = fxv[r];
                    const float top = ax + (ay - ax) * f;
                    const float bot = cx + (cy - cx) * f;
                    orow[r * 64 + lane] = top + (bot - top) * fy;
                }
            }
        }
    }
}

extern "C" void kernel_launch(void* const* d_in, const int* in_sizes, int n_in,
                              void* d_out, int out_size, void* d_ws, size_t ws_size,
                              hipStream_t stream) {
    const float* x     = (const float*)d_in[0];
    const int*   sizes = (const int*)d_in[1];
    const int*   offx  = (const int*)d_in[2];
    const int*   offy  = (const int*)d_in[3];
    float* out = (float*)d_out;

    cutouts_kernel<<<GRID, 256, 0, stream>>>(x, sizes, offx, offy, out);
}